// Round 8
// baseline (5075.447 us; speedup 1.0000x reference)
//
#include <hip/hip_runtime.h>
#include <math.h>

#define N_NODES 8192
#define NFEAT 512
#define NHID 512
#define NCLASS 8
#define RCAP 192     // max row degree; Binomial(8192,0.01): mean 82, std 9 -> 192 is ~12 sigma
#define KB_SPLIT 1536  // B operand: [hi | lo | hi] bf16
#define KA_SPLIT 1024  // A operand: [hi | lo] bf16 (chunk map re-reads hi)
#define CANDCAP 64     // score candidates within FILTER_MARGIN of row max (expected ~1.1)
#define FILTER_MARGIN 96.0f  // >= worst-case bf16-h filter error (~41) + 28 (1e-12 cutoff) + slack
#define SROWS 4        // rows per spmm block; 2048 spmm blocks = 8 blocks/CU co-resident at 4 waves

// ======== MEASUREMENT ROUND (structure = R7): inflate score2 x20 and both MFMA
// ======== gemms x12. Top-5 reveals the largest with full counters; the other
// ======== resolves from dur = 723 + 19*s + 11*(g1+g2). All reps idempotent.
#define REP_SCORE 20
#define REP_GEMM 12

// prep partition (within merged build_prep, after the 8192 build blocks)
#define PB_SPLITA 256                  // [0,256) transpose Kw
#define PB_SPLITB (PB_SPLITA + 4096)   // split_a2(x)
#define PB_SPLITV (PB_SPLITB + 768)    // split_bt(W1)
#define PB_BIAS   (PB_SPLITV + 768)    // Vw -> Bcts upper half
#define PB_MISC   (PB_BIAS + 129)      // bias_prep (4 k per block)
#define PB_TOTAL  (PB_MISC + 6)        // bcat/T init

// ---------- bf16 split helpers ----------
__device__ inline ushort f2bf(float f) {
  uint32_t u = __float_as_uint(f);
  uint32_t r = u + 0x7fffu + ((u >> 16) & 1u);
  return (ushort)(r >> 16);
}
__device__ inline float bf2f(ushort h) { return __uint_as_float(((uint32_t)h) << 16); }

// ================= L1: build_ell (b<8192) + merged prep (b>=8192) =================
__global__ __launch_bounds__(256) void build_prep(
    const float* __restrict__ adj, int* __restrict__ colidx, int* __restrict__ deg,
    const float* __restrict__ Kw, float* __restrict__ KwT,
    const float* __restrict__ x, ushort* __restrict__ Xs,
    const float* __restrict__ W1, ushort* __restrict__ W1ts,
    const float* __restrict__ Vw, ushort* __restrict__ Bcts,
    const float* __restrict__ Qw, const float* __restrict__ Qb, const float* __restrict__ Kb,
    float* __restrict__ u, float* __restrict__ w, float* __restrict__ cbuf,
    const float* __restrict__ Vb, float* __restrict__ bcat, float* __restrict__ T) {
  __shared__ int cnt;
  __shared__ int cols[RCAP];
  __shared__ float tile[32][33];
  int bid = blockIdx.x, t = threadIdx.x;
  if (bid < N_NODES) {
    // ---- build_ell: dense 0/1 -> ELL, STRICTLY band-sorted (1024-col bands) ----
    int row = bid;
    if (t == 0) cnt = 0;
    __syncthreads();
    const float4* arow = (const float4*)(adj + (size_t)row * N_NODES);
#pragma unroll
    for (int it = 0; it < N_NODES / 4 / 256; ++it) {  // 8 iterations = 8 bands of 1024 cols
      int i = it * 256 + t;
      float4 v = arow[i];
      int base = i * 4;
      if (v.x > 0.5f) { int p = atomicAdd(&cnt, 1); if (p < RCAP) cols[p] = base; }
      if (v.y > 0.5f) { int p = atomicAdd(&cnt, 1); if (p < RCAP) cols[p] = base + 1; }
      if (v.z > 0.5f) { int p = atomicAdd(&cnt, 1); if (p < RCAP) cols[p] = base + 2; }
      if (v.w > 0.5f) { int p = atomicAdd(&cnt, 1); if (p < RCAP) cols[p] = base + 3; }
      __syncthreads();  // strict band ordering across iterations
    }
    int d = cnt < RCAP ? cnt : RCAP;
    if (t == 0) deg[row] = d;
    for (int i = t; i < d; i += 256) colidx[(size_t)row * RCAP + i] = cols[i];
    return;
  }
  int b = bid - N_NODES;
  if (b < PB_SPLITA) {
    // 512x512 transpose: Kw -> KwT
    int bx = b & 15, by = b >> 4;
    int tx = t & 31, ty = t >> 5;
    int xcol = bx * 32 + tx, y0 = by * 32;
    for (int i = ty; i < 32; i += 8) tile[i][tx] = Kw[(size_t)(y0 + i) * 512 + xcol];
    __syncthreads();
    int xo = by * 32 + tx, yo0 = bx * 32;
    for (int i = ty; i < 32; i += 8) KwT[(size_t)(yo0 + i) * 512 + xo] = tile[tx][i];
  } else if (b < PB_SPLITB) {
    // split x [8192x512] -> Xs [hi|lo]
    int idx = (b - PB_SPLITA) * 256 + t;
    int m = idx >> 7, tc = idx & 127;
    float4 v = ((const float4*)(x + (size_t)m * 512))[tc];
    ushort4 hi, lo;
    hi.x = f2bf(v.x); hi.y = f2bf(v.y); hi.z = f2bf(v.z); hi.w = f2bf(v.w);
    lo.x = f2bf(v.x - bf2f(hi.x)); lo.y = f2bf(v.y - bf2f(hi.y));
    lo.z = f2bf(v.z - bf2f(hi.z)); lo.w = f2bf(v.w - bf2f(hi.w));
    ushort* row = Xs + (size_t)m * KA_SPLIT;
    ((ushort4*)row)[tc] = hi;
    ((ushort4*)(row + 512))[tc] = lo;
  } else if (b < PB_SPLITV) {
    // split+transpose W1 -> W1ts [hi|lo|hi]
    int idx = (b - PB_SPLITB) * 256 + t;
    int n = idx / 384, tc = idx % 384;
    int sec = tc >> 7;
    int k0 = (tc & 127) << 2;
    ushort4 o;
    float f0 = W1[(size_t)(k0 + 0) * 512 + n];
    float f1 = W1[(size_t)(k0 + 1) * 512 + n];
    float f2 = W1[(size_t)(k0 + 2) * 512 + n];
    float f3 = W1[(size_t)(k0 + 3) * 512 + n];
    if (sec == 1) {
      o.x = f2bf(f0 - bf2f(f2bf(f0))); o.y = f2bf(f1 - bf2f(f2bf(f1)));
      o.z = f2bf(f2 - bf2f(f2bf(f2))); o.w = f2bf(f3 - bf2f(f2bf(f3)));
    } else {
      o.x = f2bf(f0); o.y = f2bf(f1); o.z = f2bf(f2); o.w = f2bf(f3);
    }
    ((ushort4*)(W1ts + (size_t)n * KB_SPLIT))[tc] = o;
  } else if (b < PB_BIAS) {
    // Vw columns -> Bcts rows [512,1024)
    int idx = (b - PB_SPLITV) * 256 + t;
    int n = idx / 384, tc = idx % 384;
    const float* src = Vw + n;
    int sec = tc >> 7;
    int k0 = (tc & 127) << 2;
    ushort4 o;
    float f0 = src[(size_t)(k0 + 0) * 512];
    float f1 = src[(size_t)(k0 + 1) * 512];
    float f2 = src[(size_t)(k0 + 2) * 512];
    float f3 = src[(size_t)(k0 + 3) * 512];
    if (sec == 1) {
      o.x = f2bf(f0 - bf2f(f2bf(f0))); o.y = f2bf(f1 - bf2f(f2bf(f1)));
      o.z = f2bf(f2 - bf2f(f2bf(f2))); o.w = f2bf(f3 - bf2f(f2bf(f3)));
    } else {
      o.x = f2bf(f0); o.y = f2bf(f1); o.z = f2bf(f2); o.w = f2bf(f3);
    }
    ((ushort4*)(Bcts + (size_t)(512 + n) * KB_SPLIT))[tc] = o;
  } else if (b < PB_MISC) {
    // rank-1 bias helpers: one k per wave (4 waves/block)
    int k = (b - PB_BIAS) * 4 + (t >> 6);
    int lane = t & 63;
    if (k > NHID) return;
    if (k == NHID) {
      float s = 0.f;
      for (int j = lane; j < NHID; j += 64) s = fmaf(Qb[j], Kb[j], s);
#pragma unroll
      for (int o = 32; o > 0; o >>= 1) s += __shfl_down(s, o, 64);
      if (lane == 0) cbuf[0] = s;
      return;
    }
    float su = 0.f, sw = 0.f;
    for (int j = lane; j < NHID; j += 64) {
      su = fmaf(Qw[(size_t)k * NHID + j], Kb[j], su);
      sw = fmaf(Kw[(size_t)k * NHID + j], Qb[j], sw);
    }
#pragma unroll
    for (int o = 32; o > 0; o >>= 1) { su += __shfl_down(su, o, 64); sw += __shfl_down(sw, o, 64); }
    if (lane == 0) { u[k] = su; w[k] = sw; }
  } else {
    // bcat = [0 | Vb]; T = 0
    int i = (b - PB_MISC) * 256 + t;
    if (i < 1024) bcat[i] = (i < 512) ? 0.f : Vb[i - 512];
    else if (i < 1536) T[i - 1024] = 0.f;
  }
}

// ================= MFMA GEMM body (rep-looped for measurement) =================
using frag_ab = __attribute__((ext_vector_type(8))) short;
using frag_cd = __attribute__((ext_vector_type(4))) float;

__device__ void mfma_gemm_body(int bx, int by, const ushort* __restrict__ A,
                               const ushort* __restrict__ Bt, const float* __restrict__ bias,
                               float* __restrict__ C, int ldc, float* __restrict__ Tsum,
                               ushort* Atile, ushort* Btile, int reps) {
  const int tid = threadIdx.x;
  const int w = tid >> 6, lane = tid & 63;
  const int m0 = by * 128, n0 = bx * 128;
  const int wm = (w >> 1) * 64, wn = (w & 1) * 64;
  const int q = lane >> 4, c16 = lane & 15;

  const int srow = (w << 3) + (lane >> 3);
  const int scolb = (lane & 7) << 4;
  const uint8_t* gA = (const uint8_t*)A + (size_t)(m0 + srow) * (KA_SPLIT * 2) + scolb;
  const uint8_t* gB = (const uint8_t*)Bt + (size_t)(n0 + srow) * (KB_SPLIT * 2) + scolb;

  for (int rep = 0; rep < reps; ++rep) {
    frag_cd acc[4][4];
#pragma unroll
    for (int i = 0; i < 4; ++i)
#pragma unroll
      for (int j = 0; j < 4; ++j) acc[i][j] = (frag_cd){0.f, 0.f, 0.f, 0.f};

    for (int c = 0; c < 24; ++c) {
      const size_t kaB = (size_t)((c < 8 ? c : c - 8) * 128);
      const size_t kbB = (size_t)(c * 128);
#pragma unroll
      for (int r = 0; r < 4; ++r) {
        __builtin_amdgcn_global_load_lds(
            (const __attribute__((address_space(1))) uint32_t*)(gA + (size_t)(r * 32) * (KA_SPLIT * 2) + kaB),
            (__attribute__((address_space(3))) uint32_t*)((uint8_t*)Atile + r * 4096 + w * 1024), 16, 0, 0);
        __builtin_amdgcn_global_load_lds(
            (const __attribute__((address_space(1))) uint32_t*)(gB + (size_t)(r * 32) * (KB_SPLIT * 2) + kbB),
            (__attribute__((address_space(3))) uint32_t*)((uint8_t*)Btile + r * 4096 + w * 1024), 16, 0, 0);
      }
      __syncthreads();
#pragma unroll
      for (int kk = 0; kk < 2; ++kk) {
        frag_ab af[4], bf[4];
#pragma unroll
        for (int i = 0; i < 4; ++i) {
          af[i] = *(const frag_ab*)((const uint8_t*)Atile + (wm + i * 16 + c16) * 128 + kk * 64 + q * 16);
          bf[i] = *(const frag_ab*)((const uint8_t*)Btile + (wn + i * 16 + c16) * 128 + kk * 64 + q * 16);
        }
#pragma unroll
        for (int i = 0; i < 4; ++i)
#pragma unroll
          for (int j = 0; j < 4; ++j)
            acc[i][j] = __builtin_amdgcn_mfma_f32_16x16x32_bf16(af[i], bf[j], acc[i][j], 0, 0, 0);
      }
      __syncthreads();
    }
    // C/D layout: col = lane&15, row = (lane>>4)*4 + reg
#pragma unroll
    for (int j = 0; j < 4; ++j) {
      int col = n0 + wn + j * 16 + c16;
      float bv = bias ? bias[col] : 0.f;
      float csum = 0.f;
#pragma unroll
      for (int i = 0; i < 4; ++i) {
        int row = m0 + wm + i * 16 + q * 4;
#pragma unroll
        for (int r = 0; r < 4; ++r) {
          float v = acc[i][j][r] + bv;
          C[(size_t)(row + r) * ldc + col] = v;
          csum += v;
        }
      }
      if (Tsum && col >= 512 && rep + 1 == reps) {  // fused T = colsum(Vh), last rep only
        csum += __shfl_xor(csum, 16, 64);
        csum += __shfl_xor(csum, 32, 64);
        if (q == 0) atomicAdd(&Tsum[col - 512], csum);
      }
    }
    asm volatile("" ::: "memory");
  }
}

// ---------------- fp32 SGEMM body (small 512^3: M = Qw@Kw^T) ----------------
__device__ void sgemm_body(int bx, int by, const float* __restrict__ A, const float* __restrict__ B,
                           float* __restrict__ C, char* smem) {
  float(*As)[68] = (float(*)[68])smem;
  float(*Bs)[132] = (float(*)[132])(smem + 16 * 68 * 4);
  const int M = 512, Nn = 512, K = 512, ldc = 512;
  const int tid = threadIdx.x;
  const int bm = by * 64, bn = bx * 128;
  const int tx = tid & 15, ty = tid >> 4;
  const int arow = tid >> 2, acol = (tid & 3) << 2;
  const int brow = tid >> 4, bcol = (tid & 15) << 2;
  float acc[4][8];
#pragma unroll
  for (int i = 0; i < 4; ++i)
#pragma unroll
    for (int j = 0; j < 8; ++j) acc[i][j] = 0.f;
  const float* Ap = A + (size_t)(bm + arow) * K + acol;
  const float* Bp = B + (size_t)brow * Nn + bn + bcol;
  float4 av = *(const float4*)(Ap);
  float4 bv0 = *(const float4*)(Bp);
  float4 bv1 = *(const float4*)(Bp + 64);
  for (int k0 = 0; k0 < K; k0 += 16) {
    if (k0) __syncthreads();
    As[acol + 0][arow] = av.x;
    As[acol + 1][arow] = av.y;
    As[acol + 2][arow] = av.z;
    As[acol + 3][arow] = av.w;
    *(float4*)&Bs[brow][bcol] = bv0;
    *(float4*)&Bs[brow][bcol + 64] = bv1;
    __syncthreads();
    int kn = (k0 + 16 < K) ? k0 + 16 : 0;
    av = *(const float4*)(Ap + kn);
    bv0 = *(const float4*)(Bp + (size_t)kn * Nn);
    bv1 = *(const float4*)(Bp + (size_t)kn * Nn + 64);
#pragma unroll
    for (int kk = 0; kk < 16; ++kk) {
      float4 a = *(const float4*)&As[kk][ty << 2];
      float4 b0 = *(const float4*)&Bs[kk][tx << 2];
      float4 b1 = *(const float4*)&Bs[kk][(tx << 2) + 64];
      float ar[4] = {a.x, a.y, a.z, a.w};
      float br[8] = {b0.x, b0.y, b0.z, b0.w, b1.x, b1.y, b1.z, b1.w};
#pragma unroll
      for (int i = 0; i < 4; ++i)
#pragma unroll
        for (int j = 0; j < 8; ++j) acc[i][j] = fmaf(ar[i], br[j], acc[i][j]);
    }
  }
#pragma unroll
  for (int i = 0; i < 4; ++i) {
    int r = bm + (ty << 2) + i;
    *(float4*)(C + (size_t)r * ldc + bn + (tx << 2)) =
        make_float4(acc[i][0], acc[i][1], acc[i][2], acc[i][3]);
    *(float4*)(C + (size_t)r * ldc + bn + 64 + (tx << 2)) =
        make_float4(acc[i][4], acc[i][5], acc[i][6], acc[i][7]);
  }
  (void)M;
}

// ================= L2: gemm1 (xW = x@W1, 256 blocks, x12) + sgemm (32 blocks, x1) =================
__global__ __launch_bounds__(256) void gemm1_sgemm(
    const ushort* __restrict__ Xs, const ushort* __restrict__ W1ts, float* __restrict__ xW,
    const float* __restrict__ Qw, const float* __restrict__ KwT, float* __restrict__ Mmat,
    int reps) {
  __shared__ __align__(16) char smem[32768];
  int b = blockIdx.x;
  if (b < 256) {
    mfma_gemm_body(b & 3, b >> 2, Xs, W1ts, nullptr, xW, 512, nullptr,
                   (ushort*)smem, (ushort*)(smem + 16384), reps);
  } else {
    sgemm_body((b - 256) & 3, (b - 256) >> 2, Qw, KwT, Mmat, smem);
  }
}

// ================= gemm2 standalone: [G|Vh] = h@[M|Vw] + bias, fused T (x12) =================
__global__ __launch_bounds__(256) void mfma_gemm2(const ushort* __restrict__ Hs,
                                                  const ushort* __restrict__ Bcts,
                                                  const float* __restrict__ bcat,
                                                  float* __restrict__ GVh, float* __restrict__ T,
                                                  int reps) {
  __shared__ __align__(16) ushort Atile[128 * 64];
  __shared__ __align__(16) ushort Btile[128 * 64];
  mfma_gemm_body(blockIdx.x, blockIdx.y, Hs, Bcts, bcat, GVh, 1024, T, Atile, Btile, reps);
}

// ================= L3: spmm (2048 blocks) + split_mmat (768 blocks) =================
__global__ __launch_bounds__(256, 8) void spmm_split(
    const float* __restrict__ xW, const int* __restrict__ colidx, const int* __restrict__ deg,
    const float* __restrict__ b1, const float* __restrict__ u, const float* __restrict__ w,
    float* __restrict__ h, ushort* __restrict__ Hs,
    float* __restrict__ a_vec, float* __restrict__ b_vec,
    const float* __restrict__ Mm, ushort* __restrict__ Bt) {
  __shared__ int scols[SROWS][RCAP];
  __shared__ float4 part[128];
  __shared__ float ra[2], rb[2];
  int t = threadIdx.x;
  if (blockIdx.x >= N_NODES / SROWS) {
    // ---- split_mmat: Mmat columns -> Bcts rows [0,512) ----
    int idx = (blockIdx.x - N_NODES / SROWS) * 256 + t;
    int n = idx / 384, tc = idx % 384;
    const float* src = Mm + n;
    int sec = tc >> 7;
    int k0 = (tc & 127) << 2;
    ushort4 o;
    float f0 = src[(size_t)(k0 + 0) * 512];
    float f1 = src[(size_t)(k0 + 1) * 512];
    float f2 = src[(size_t)(k0 + 2) * 512];
    float f3 = src[(size_t)(k0 + 3) * 512];
    if (sec == 1) {
      o.x = f2bf(f0 - bf2f(f2bf(f0))); o.y = f2bf(f1 - bf2f(f2bf(f1)));
      o.z = f2bf(f2 - bf2f(f2bf(f2))); o.w = f2bf(f3 - bf2f(f2bf(f3)));
    } else {
      o.x = f2bf(f0); o.y = f2bf(f1); o.z = f2bf(f2); o.w = f2bf(f3);
    }
    ((ushort4*)(Bt + (size_t)n * KB_SPLIT))[tc] = o;
    return;
  }
  int half = t >> 7, tt = t & 127;
  int row0 = blockIdx.x * SROWS;
  int d[SROWS];
#pragma unroll
  for (int r = 0; r < SROWS; ++r) {
    d[r] = deg[row0 + r];
    for (int i = t; i < d[r]; i += 256) scols[r][i] = colidx[(size_t)(row0 + r) * RCAP + i];
  }
  __syncthreads();
#pragma unroll 1
  for (int r = 0; r < SROWS; ++r) {
    int row = row0 + r, dd = d[r];
    float4 acc = make_float4(0.f, 0.f, 0.f, 0.f);
    int e = half;  // this half takes edges of parity `half` (stride 2) -> same band phase
    for (; e + 14 < dd; e += 16) {
      float4 v0 = ((const float4*)(xW + (size_t)scols[r][e + 0] * NHID))[tt];
      float4 v1 = ((const float4*)(xW + (size_t)scols[r][e + 2] * NHID))[tt];
      float4 v2 = ((const float4*)(xW + (size_t)scols[r][e + 4] * NHID))[tt];
      float4 v3 = ((const float4*)(xW + (size_t)scols[r][e + 6] * NHID))[tt];
      float4 v4 = ((const float4*)(xW + (size_t)scols[r][e + 8] * NHID))[tt];
      float4 v5 = ((const float4*)(xW + (size_t)scols[r][e + 10] * NHID))[tt];
      float4 v6 = ((const float4*)(xW + (size_t)scols[r][e + 12] * NHID))[tt];
      float4 v7 = ((const float4*)(xW + (size_t)scols[r][e + 14] * NHID))[tt];
      acc.x += ((v0.x + v1.x) + (v2.x + v3.x)) + ((v4.x + v5.x) + (v6.x + v7.x));
      acc.y += ((v0.y + v1.y) + (v2.y + v3.y)) + ((v4.y + v5.y) + (v6.y + v7.y));
      acc.z += ((v0.z + v1.z) + (v2.z + v3.z)) + ((v4.z + v5.z) + (v6.z + v7.z));
      acc.w += ((v0.w + v1.w) + (v2.w + v3.w)) + ((v4.w + v5.w) + (v6.w + v7.w));
    }
    for (; e < dd; e += 2) {
      float4 v = ((const float4*)(xW + (size_t)scols[r][e] * NHID))[tt];
      acc.x += v.x; acc.y += v.y; acc.z += v.z; acc.w += v.w;
    }
    if (half == 1) part[tt] = acc;
    __syncthreads();
    if (half == 0) {
      float4 p = part[tt];
      acc.x += p.x; acc.y += p.y; acc.z += p.z; acc.w += p.w;
      float4 bv = ((const float4*)b1)[tt];
      float4 o = make_float4(fmaxf(acc.x + bv.x, 0.f), fmaxf(acc.y + bv.y, 0.f),
                             fmaxf(acc.z + bv.z, 0.f), fmaxf(acc.w + bv.w, 0.f));
      ((float4*)(h + (size_t)row * NHID))[tt] = o;
      ushort4 hi, lo;
      hi.x = f2bf(o.x); hi.y = f2bf(o.y); hi.z = f2bf(o.z); hi.w = f2bf(o.w);
      lo.x = f2bf(o.x - bf2f(hi.x)); lo.y = f2bf(o.y - bf2f(hi.y));
      lo.z = f2bf(o.z - bf2f(hi.z)); lo.w = f2bf(o.w - bf2f(hi.w));
      ushort* hr = Hs + (size_t)row * KA_SPLIT;
      ((ushort4*)hr)[tt] = hi;
      ((ushort4*)(hr + 512))[tt] = lo;
      float4 uv = ((const float4*)u)[tt], wv4 = ((const float4*)w)[tt];
      float sa = fmaf(o.x, uv.x, fmaf(o.y, uv.y, fmaf(o.z, uv.z, o.w * uv.w)));
      float sb = fmaf(o.x, wv4.x, fmaf(o.y, wv4.y, fmaf(o.z, wv4.z, o.w * wv4.w)));
      int wid = tt >> 6, lane = tt & 63;
#pragma unroll
      for (int off = 32; off > 0; off >>= 1) { sa += __shfl_down(sa, off, 64); sb += __shfl_down(sb, off, 64); }
      if (lane == 0) { ra[wid] = sa; rb[wid] = sb; }
    }
    __syncthreads();
    if (t == 0) { a_vec[row] = ra[0] + ra[1]; b_vec[row] = rb[0] + rb[1]; }
    __syncthreads();
  }
}

// ================= L5: score2 (rep-looped x20 for measurement) =================
__global__ __launch_bounds__(256) void score2_agg_ln(
    const float* __restrict__ G, int ldg, const float* __restrict__ h,
    const ushort* __restrict__ Hs, const int* __restrict__ colidx, const int* __restrict__ deg,
    const float* __restrict__ a_vec, const float* __restrict__ b_vec,
    const float* __restrict__ cbuf, const float* __restrict__ Vh, int ldv,
    const float* __restrict__ T, const float* __restrict__ lng,
    const float* __restrict__ lnb, const float* __restrict__ W2, float* __restrict__ Y,
    int reps) {
  __shared__ int scols[4][RCAP];
  __shared__ float sbv[4][RCAP];
  __shared__ float sv[4][RCAP];
  __shared__ int cand[4][CANDCAP];
  __shared__ int ccnt[4];
  __shared__ float w2s[NHID * NCLASS];
  int t = threadIdx.x, wv = t >> 6, lane = t & 63;
  int row = blockIdx.x * 4 + wv;
  int d = deg[row];
  int q = lane >> 4, u = lane & 15;
  for (int i = t; i < NHID * NCLASS; i += 256) w2s[i] = W2[i];
  float4 ga4[4][2];
  const float4* Gr4 = (const float4*)(G + (size_t)row * ldg);
#pragma unroll
  for (int it2 = 0; it2 < 4; ++it2) {
    ga4[it2][0] = Gr4[it2 * 32 + 2 * u];
    ga4[it2][1] = Gr4[it2 * 32 + 2 * u + 1];
  }
  for (int i = lane; i < d; i += 64) {
    int c = colidx[(size_t)row * RCAP + i];
    scols[wv][i] = c;
    sbv[wv][i] = b_vec[c];
  }
  float ai = a_vec[row] + cbuf[0];
  for (int rep = 0; rep < reps; ++rep) {
    if (lane == 0) ccnt[wv] = 0;
    __syncthreads();
    // ---- Phase A: filter scores from bf16 h-hi (1 KB gathers, band-sorted order) ----
    for (int e0 = 0; e0 < d; e0 += 4) {
      int e = e0 + q;
      bool act = e < d;
      int col = scols[wv][act ? e : 0];
      const uint4* hr = (const uint4*)(Hs + (size_t)col * KA_SPLIT);  // hi = first 1 KB
      float s_a = 0.f, s_b = 0.f;
#pragma unroll
      for (int it2 = 0; it2 < 4; ++it2) {
        uint4 p = hr[it2 * 16 + u];
        float4 g0 = ga4[it2][0], g1 = ga4[it2][1];
        s_a = fmaf(__uint_as_float(p.x << 16), g0.x, s_a);
        s_a = fmaf(__uint_as_float(p.x & 0xffff0000u), g0.y, s_a);
        s_a = fmaf(__uint_as_float(p.y << 16), g0.z, s_a);
        s_a = fmaf(__uint_as_float(p.y & 0xffff0000u), g0.w, s_a);
        s_b = fmaf(__uint_as_float(p.z << 16), g1.x, s_b);
        s_b = fmaf(__uint_as_float(p.z & 0xffff0000u), g1.y, s_b);
        s_b = fmaf(__uint_as_float(p.w << 16), g1.z, s_b);
        s_b = fmaf(__uint_as_float(p.w & 0xffff0000u), g1.w, s_b);
      }
      float s = s_a + s_b;
      s += __shfl_down(s, 8, 16);
      s += __shfl_down(s, 4, 16);
      s += __shfl_down(s, 2, 16);
      s += __shfl_down(s, 1, 16);
      if (u == 0 && act) sv[wv][e] = s + sbv[wv][e];
    }
    __syncthreads();
    float fm = -1e30f;
    for (int i = lane; i < d; i += 64) fm = fmaxf(fm, sv[wv][i]);
#pragma unroll
    for (int o = 32; o > 0; o >>= 1) fm = fmaxf(fm, __shfl_xor(fm, o, 64));
    for (int i = lane; i < d; i += 64) {
      if (sv[wv][i] >= fm - FILTER_MARGIN) {
        int p = atomicAdd(&ccnt[wv], 1);
        if (p < CANDCAP) cand[wv][p] = i;
      }
    }
    __syncthreads();
    int nc = ccnt[wv];
    bool ovf = nc > CANDCAP;
    if (ovf) nc = d;
    // ---- Phase B: exact fp32 rescore of candidates ----
    for (int c0 = 0; c0 < nc; c0 += 4) {
      int idx = c0 + q;
      bool act = idx < nc;
      int e = act ? (ovf ? idx : cand[wv][idx]) : 0;
      int col = scols[wv][e];
      const float4* hr = (const float4*)(h + (size_t)col * NHID);
      float s_a = 0.f, s_b = 0.f;
#pragma unroll
      for (int it2 = 0; it2 < 4; ++it2) {
        float4 h0 = hr[it2 * 32 + 2 * u], h1 = hr[it2 * 32 + 2 * u + 1];
        float4 g0 = ga4[it2][0], g1 = ga4[it2][1];
        s_a = fmaf(h0.x, g0.x, s_a); s_a = fmaf(h0.y, g0.y, s_a);
        s_a = fmaf(h0.z, g0.z, s_a); s_a = fmaf(h0.w, g0.w, s_a);
        s_b = fmaf(h1.x, g1.x, s_b); s_b = fmaf(h1.y, g1.y, s_b);
        s_b = fmaf(h1.z, g1.z, s_b); s_b = fmaf(h1.w, g1.w, s_b);
      }
      float s = s_a + s_b;
      s += __shfl_down(s, 8, 16);
      s += __shfl_down(s, 4, 16);
      s += __shfl_down(s, 2, 16);
      s += __shfl_down(s, 1, 16);
      if (u == 0 && act) sv[wv][e] = s + ai + sbv[wv][e];
    }
    __syncthreads();
    float m = 0.f;
    for (int i = lane; i < nc; i += 64) {
      int e = ovf ? i : cand[wv][i];
      m = fmaxf(m, sv[wv][e]);
    }
#pragma unroll
    for (int o = 32; o > 0; o >>= 1) m = fmaxf(m, __shfl_xor(m, o, 64));
    float ssum = 0.f;
    for (int i = lane; i < nc; i += 64) {
      int e = ovf ? i : cand[wv][i];
      float ex = expf(sv[wv][e] - m);
      sv[wv][e] = ex;
      ssum += ex;
    }
#pragma unroll
    for (int o = 32; o > 0; o >>= 1) ssum += __shfl_xor(ssum, o, 64);
    float em = expf(-m);
    float inv = 1.f / (ssum + (float)(N_NODES - d) * em);
    float ci = em * inv;
    __syncthreads();
    float4 a0 = make_float4(0.f, 0.f, 0.f, 0.f), a1 = a0;
    for (int i = 0; i < nc; ++i) {
      int e = ovf ? i : cand[wv][i];
      float we = sv[wv][e] * inv;
      if (we > 1e-12f) {
        const float4* vr = (const float4*)(Vh + (size_t)scols[wv][e] * ldv);
        float4 v0 = vr[lane * 2], v1 = vr[lane * 2 + 1];
        a0.x = fmaf(we, v0.x, a0.x); a0.y = fmaf(we, v0.y, a0.y);
        a0.z = fmaf(we, v0.z, a0.z); a0.w = fmaf(we, v0.w, a0.w);
        a1.x = fmaf(we, v1.x, a1.x); a1.y = fmaf(we, v1.y, a1.y);
        a1.z = fmaf(we, v1.z, a1.z); a1.w = fmaf(we, v1.w, a1.w);
      }
    }
    float4 t0 = ((const float4*)T)[lane * 2], t1 = ((const float4*)T)[lane * 2 + 1];
    a0.x = fmaf(ci, t0.x, a0.x); a0.y = fmaf(ci, t0.y, a0.y);
    a0.z = fmaf(ci, t0.z, a0.z); a0.w = fmaf(ci, t0.w, a0.w);
    a1.x = fmaf(ci, t1.x, a1.x); a1.y = fmaf(ci, t1.y, a1.y);
    a1.z = fmaf(ci, t1.z, a1.z); a1.w = fmaf(ci, t1.w, a1.w);
    float s1 = ((a0.x + a0.y) + (a0.z + a0.w)) + ((a1.x + a1.y) + (a1.z + a1.w));
    float s2 = ((a0.x * a0.x + a0.y * a0.y) + (a0.z * a0.z + a0.w * a0.w)) +
               ((a1.x * a1.x + a1.y * a1.y) + (a1.z * a1.z + a1.w * a1.w));
#pragma unroll
    for (int o = 32; o > 0; o >>= 1) { s1 += __shfl_xor(s1, o, 64); s2 += __shfl_xor(s2, o, 64); }
    float mu = s1 * (1.f / NHID);
    float var = s2 * (1.f / NHID) - mu * mu;
    float rstd = rsqrtf(var + 1e-5f);
    float4 g0 = ((const float4*)lng)[lane * 2], g1 = ((const float4*)lng)[lane * 2 + 1];
    float4 b0 = ((const float4*)lnb)[lane * 2], b1v = ((const float4*)lnb)[lane * 2 + 1];
    float4 o0, o1;
    o0.x = (a0.x - mu) * rstd * g0.x + b0.x;
    o0.y = (a0.y - mu) * rstd * g0.y + b0.y;
    o0.z = (a0.z - mu) * rstd * g0.z + b0.z;
    o0.w = (a0.w - mu) * rstd * g0.w + b0.w;
    o1.x = (a1.x - mu) * rstd * g1.x + b1v.x;
    o1.y = (a1.y - mu) * rstd * g1.y + b1v.y;
    o1.z = (a1.z - mu) * rstd * g1.z + b1v.z;
    o1.w = (a1.w - mu) * rstd * g1.w + b1v.w;
    float xv[8] = {o0.x, o0.y, o0.z, o0.w, o1.x, o1.y, o1.z, o1.w};
    float accc[NCLASS];
#pragma unroll
    for (int c = 0; c < NCLASS; ++c) accc[c] = 0.f;
#pragma unroll
    for (int kk = 0; kk < 8; ++kk) {
      int k = lane * 8 + kk;
#pragma unroll
      for (int c = 0; c < NCLASS; ++c) accc[c] = fmaf(xv[kk], w2s[k * NCLASS + c], accc[c]);
    }
#pragma unroll
    for (int c = 0; c < NCLASS; ++c)
#pragma unroll
      for (int o = 32; o > 0; o >>= 1) accc[c] += __shfl_down(accc[c], o, 64);
    if (lane == 0) {
      *(float4*)(Y + (size_t)row * NCLASS) = make_float4(accc[0], accc[1], accc[2], accc[3]);
      *(float4*)(Y + (size_t)row * NCLASS + 4) = make_float4(accc[4], accc[5], accc[6], accc[7]);
    }
    __syncthreads();
    asm volatile("" ::: "memory");
  }
}

// ================= L6: z = adj @ Y + b2, softmax over 8 classes =================
__global__ __launch_bounds__(256) void final_spmm_softmax(const float* __restrict__ Y,
                                                          const int* __restrict__ colidx,
                                                          const int* __restrict__ deg,
                                                          const float* __restrict__ b2,
                                                          float* __restrict__ out) {
  int t = threadIdx.x;
  int wv = t >> 6, lane = t & 63;
  int row = blockIdx.x * 4 + wv;
  int d = deg[row];
  const int* cols = colidx + (size_t)row * RCAP;
  float acc[8];
#pragma unroll
  for (int c = 0; c < 8; ++c) acc[c] = 0.f;
  for (int e = lane; e < d; e += 64) {
    int col = cols[e];
    const float4* yr = (const float4*)(Y + (size_t)col * 8);
    float4 y0 = yr[0], y1 = yr[1];
    acc[0] += y0.x; acc[1] += y0.y; acc[2] += y0.z; acc[3] += y0.w;
    acc[4] += y1.x; acc[5] += y1.y; acc[6] += y1.z; acc[7] += y1.w;
  }
#pragma unroll
  for (int c = 0; c < 8; ++c)
#pragma unroll
    for (int o = 32; o > 0; o >>= 1) acc[c] += __shfl_down(acc[c], o, 64);
  if (lane == 0) {
    float z[8];
    float m = -1e30f;
#pragma unroll
    for (int c = 0; c < 8; ++c) { z[c] = acc[c] + b2[c]; m = fmaxf(m, z[c]); }
    float s = 0.f;
#pragma unroll
    for (int c = 0; c < 8; ++c) { z[c] = expf(z[c] - m); s += z[c]; }
    float inv = 1.f / s;
    *(float4*)(out + (size_t)row * 8) = make_float4(z[0] * inv, z[1] * inv, z[2] * inv, z[3] * inv);
    *(float4*)(out + (size_t)row * 8 + 4) = make_float4(z[4] * inv, z[5] * inv, z[6] * inv, z[7] * inv);
  }
}

extern "C" void kernel_launch(void* const* d_in, const int* in_sizes, int n_in,
                              void* d_out, int out_size, void* d_ws, size_t ws_size,
                              hipStream_t stream) {
  const float* adj = (const float*)d_in[0];
  const float* x = (const float*)d_in[1];
  const float* W1 = (const float*)d_in[2];
  const float* b1 = (const float*)d_in[3];
  const float* Qw = (const float*)d_in[4];
  const float* Qb = (const float*)d_in[5];
  const float* Kw = (const float*)d_in[6];
  const float* Kb = (const float*)d_in[7];
  const float* Vw = (const float*)d_in[8];
  const float* Vb = (const float*)d_in[9];
  const float* ln_g = (const float*)d_in[10];
  const float* ln_b = (const float*)d_in[11];
  const float* W2 = (const float*)d_in[12];
  const float* b2 = (const float*)d_in[13];
  float* out = (float*)d_out;

  char* ws = (char*)d_ws;
  size_t off = 0;
  auto alloc = [&](size_t bytes) -> void* {
    void* p = ws + off;
    off = (off + bytes + 255) & ~(size_t)255;
    return p;
  };
  int* colidx = (int*)alloc((size_t)N_NODES * RCAP * 4);
  int* deg = (int*)alloc((size_t)N_NODES * 4);
  float* bufA = (float*)alloc((size_t)N_NODES * NHID * 4);     // xW
  float* bufB = (float*)alloc((size_t)N_NODES * NHID * 4);     // h
  float* GVh = (float*)alloc((size_t)N_NODES * 1024 * 4);      // [G | Vh], stride 1024
  ushort* Xs = (ushort*)alloc((size_t)N_NODES * KA_SPLIT * 2); // split x [hi|lo]
  ushort* Hs = (ushort*)alloc((size_t)N_NODES * KA_SPLIT * 2); // split h [hi|lo]
  ushort* W1ts = (ushort*)alloc((size_t)512 * KB_SPLIT * 2);   // split W1^T [hi|lo|hi]
  ushort* Bcts = (ushort*)alloc((size_t)1024 * KB_SPLIT * 2);  // split [M|Vw]^T
  float* KwT = (float*)alloc((size_t)512 * 512 * 4);
  float* Mmat = (float*)alloc((size_t)512 * 512 * 4);
  float* bcat = (float*)alloc((size_t)1024 * 4);
  float* a_vec = (float*)alloc((size_t)N_NODES * 4);
  float* b_vec = (float*)alloc((size_t)N_NODES * 4);
  float* u_vec = (float*)alloc((size_t)NHID * 4);
  float* w_vec = (float*)alloc((size_t)NHID * 4);
  float* cbuf = (float*)alloc(256);
  float* T = (float*)alloc((size_t)NHID * 4);
  float* Y = (float*)alloc((size_t)N_NODES * NCLASS * 4);
  (void)in_sizes; (void)n_in; (void)out_size; (void)ws_size;

  // L1) build_ell + all input prep (independent work, one launch)
  build_prep<<<N_NODES + PB_TOTAL, 256, 0, stream>>>(
      adj, colidx, deg, Kw, KwT, x, Xs, W1, W1ts, Vw, Bcts,
      Qw, Qb, Kb, u_vec, w_vec, cbuf, Vb, bcat, T);
  // L2) xW = x@W1 (MFMA, x12) + M = Qw@Kw^T (fp32, x1)
  gemm1_sgemm<<<256 + 32, 256, 0, stream>>>(Xs, W1ts, bufA, Qw, KwT, Mmat, REP_GEMM);
  // L3) h = relu(adj@xW + b1) (band-swept co-resident SpMM) + Mmat->Bcts split
  spmm_split<<<N_NODES / SROWS + 768, 256, 0, stream>>>(
      bufA, colidx, deg, b1, u_vec, w_vec, bufB, Hs, a_vec, b_vec, Mmat, Bcts);
  // L4) [G | Vh] = h @ [M | Vw] (+[0|Vb]) via MFMA, fused T = colsum(Vh)  [x12]
  mfma_gemm2<<<dim3(8, 64), 256, 0, stream>>>(Hs, Bcts, bcat, GVh, T, REP_GEMM);
  // L5) two-level scores + softmax + aggregate + LN + fused W2 -> Y  [x20]
  score2_agg_ln<<<N_NODES / 4, 256, 0, stream>>>(GVh, 1024, bufB, Hs, colidx, deg, a_vec, b_vec,
                                                 cbuf, GVh + 512, 1024, T, ln_g, ln_b, W2, Y,
                                                 REP_SCORE);
  // L6) z = adj @ Y + b2 ; softmax
  final_spmm_softmax<<<N_NODES / 4, 256, 0, stream>>>(Y, colidx, deg, b2, out);
}

// Round 9
// 716.865 us; speedup vs baseline: 7.0801x; 7.0801x over previous
//
#include <hip/hip_runtime.h>
#include <math.h>

#define N_NODES 8192
#define NFEAT 512
#define NHID 512
#define NCLASS 8
#define RCAP 192     // max row degree; Binomial(8192,0.01): mean 82, std 9 -> 192 is ~12 sigma
#define KB_SPLIT 1536  // B operand: [hi | lo | hi] bf16
#define KA_SPLIT 1024  // A operand: [hi | lo] bf16 (chunk map re-reads hi)
#define CANDCAP 64     // score candidates within FILTER_MARGIN of row max (expected ~1.1)
#define FILTER_MARGIN 96.0f  // >= worst-case bf16-h filter error (~41) + 28 (1e-12 cutoff) + slack
#define SROWS 4        // rows per spmm block; 2048 spmm blocks = 8 blocks/CU co-resident at 4 waves

// prep partition (within merged build_prep, after the 8192 build blocks)
#define PB_SPLITA 256                  // [0,256) transpose Kw
#define PB_SPLITB (PB_SPLITA + 4096)   // split_a2(x)
#define PB_SPLITV (PB_SPLITB + 768)    // split_bt(W1)
#define PB_BIAS   (PB_SPLITV + 768)    // Vw -> Bcts upper half
#define PB_MISC   (PB_BIAS + 129)      // bias_prep (4 k per block)
#define PB_TOTAL  (PB_MISC + 6)        // bcat/T init

// ---------- bf16 split helpers ----------
__device__ inline ushort f2bf(float f) {
  uint32_t u = __float_as_uint(f);
  uint32_t r = u + 0x7fffu + ((u >> 16) & 1u);
  return (ushort)(r >> 16);
}
__device__ inline float bf2f(ushort h) { return __uint_as_float(((uint32_t)h) << 16); }

// ================= L1: build_ell (b<8192) + merged prep (b>=8192) =================
__global__ __launch_bounds__(256) void build_prep(
    const float* __restrict__ adj, int* __restrict__ colidx, int* __restrict__ deg,
    const float* __restrict__ Kw, float* __restrict__ KwT,
    const float* __restrict__ x, ushort* __restrict__ Xs,
    const float* __restrict__ W1, ushort* __restrict__ W1ts,
    const float* __restrict__ Vw, ushort* __restrict__ Bcts,
    const float* __restrict__ Qw, const float* __restrict__ Qb, const float* __restrict__ Kb,
    float* __restrict__ u, float* __restrict__ w, float* __restrict__ cbuf,
    const float* __restrict__ Vb, float* __restrict__ bcat, float* __restrict__ T) {
  __shared__ int cnt;
  __shared__ int cols[RCAP];
  __shared__ float tile[32][33];
  int bid = blockIdx.x, t = threadIdx.x;
  if (bid < N_NODES) {
    // ---- build_ell: dense 0/1 -> ELL, STRICTLY band-sorted (1024-col bands) ----
    int row = bid;
    if (t == 0) cnt = 0;
    __syncthreads();
    const float4* arow = (const float4*)(adj + (size_t)row * N_NODES);
#pragma unroll
    for (int it = 0; it < N_NODES / 4 / 256; ++it) {  // 8 iterations = 8 bands of 1024 cols
      int i = it * 256 + t;
      float4 v = arow[i];
      int base = i * 4;
      if (v.x > 0.5f) { int p = atomicAdd(&cnt, 1); if (p < RCAP) cols[p] = base; }
      if (v.y > 0.5f) { int p = atomicAdd(&cnt, 1); if (p < RCAP) cols[p] = base + 1; }
      if (v.z > 0.5f) { int p = atomicAdd(&cnt, 1); if (p < RCAP) cols[p] = base + 2; }
      if (v.w > 0.5f) { int p = atomicAdd(&cnt, 1); if (p < RCAP) cols[p] = base + 3; }
      __syncthreads();  // strict band ordering across iterations
    }
    int d = cnt < RCAP ? cnt : RCAP;
    if (t == 0) deg[row] = d;
    for (int i = t; i < d; i += 256) colidx[(size_t)row * RCAP + i] = cols[i];
    return;
  }
  int b = bid - N_NODES;
  if (b < PB_SPLITA) {
    // 512x512 transpose: Kw -> KwT
    int bx = b & 15, by = b >> 4;
    int tx = t & 31, ty = t >> 5;
    int xcol = bx * 32 + tx, y0 = by * 32;
    for (int i = ty; i < 32; i += 8) tile[i][tx] = Kw[(size_t)(y0 + i) * 512 + xcol];
    __syncthreads();
    int xo = by * 32 + tx, yo0 = bx * 32;
    for (int i = ty; i < 32; i += 8) KwT[(size_t)(yo0 + i) * 512 + xo] = tile[tx][i];
  } else if (b < PB_SPLITB) {
    // split x [8192x512] -> Xs [hi|lo]
    int idx = (b - PB_SPLITA) * 256 + t;
    int m = idx >> 7, tc = idx & 127;
    float4 v = ((const float4*)(x + (size_t)m * 512))[tc];
    ushort4 hi, lo;
    hi.x = f2bf(v.x); hi.y = f2bf(v.y); hi.z = f2bf(v.z); hi.w = f2bf(v.w);
    lo.x = f2bf(v.x - bf2f(hi.x)); lo.y = f2bf(v.y - bf2f(hi.y));
    lo.z = f2bf(v.z - bf2f(hi.z)); lo.w = f2bf(v.w - bf2f(hi.w));
    ushort* row = Xs + (size_t)m * KA_SPLIT;
    ((ushort4*)row)[tc] = hi;
    ((ushort4*)(row + 512))[tc] = lo;
  } else if (b < PB_SPLITV) {
    // split+transpose W1 -> W1ts [hi|lo|hi]
    int idx = (b - PB_SPLITB) * 256 + t;
    int n = idx / 384, tc = idx % 384;
    int sec = tc >> 7;
    int k0 = (tc & 127) << 2;
    ushort4 o;
    float f0 = W1[(size_t)(k0 + 0) * 512 + n];
    float f1 = W1[(size_t)(k0 + 1) * 512 + n];
    float f2 = W1[(size_t)(k0 + 2) * 512 + n];
    float f3 = W1[(size_t)(k0 + 3) * 512 + n];
    if (sec == 1) {
      o.x = f2bf(f0 - bf2f(f2bf(f0))); o.y = f2bf(f1 - bf2f(f2bf(f1)));
      o.z = f2bf(f2 - bf2f(f2bf(f2))); o.w = f2bf(f3 - bf2f(f2bf(f3)));
    } else {
      o.x = f2bf(f0); o.y = f2bf(f1); o.z = f2bf(f2); o.w = f2bf(f3);
    }
    ((ushort4*)(W1ts + (size_t)n * KB_SPLIT))[tc] = o;
  } else if (b < PB_BIAS) {
    // Vw columns -> Bcts rows [512,1024)
    int idx = (b - PB_SPLITV) * 256 + t;
    int n = idx / 384, tc = idx % 384;
    const float* src = Vw + n;
    int sec = tc >> 7;
    int k0 = (tc & 127) << 2;
    ushort4 o;
    float f0 = src[(size_t)(k0 + 0) * 512];
    float f1 = src[(size_t)(k0 + 1) * 512];
    float f2 = src[(size_t)(k0 + 2) * 512];
    float f3 = src[(size_t)(k0 + 3) * 512];
    if (sec == 1) {
      o.x = f2bf(f0 - bf2f(f2bf(f0))); o.y = f2bf(f1 - bf2f(f2bf(f1)));
      o.z = f2bf(f2 - bf2f(f2bf(f2))); o.w = f2bf(f3 - bf2f(f2bf(f3)));
    } else {
      o.x = f2bf(f0); o.y = f2bf(f1); o.z = f2bf(f2); o.w = f2bf(f3);
    }
    ((ushort4*)(Bcts + (size_t)(512 + n) * KB_SPLIT))[tc] = o;
  } else if (b < PB_MISC) {
    // rank-1 bias helpers: one k per wave (4 waves/block)
    int k = (b - PB_BIAS) * 4 + (t >> 6);
    int lane = t & 63;
    if (k > NHID) return;
    if (k == NHID) {
      float s = 0.f;
      for (int j = lane; j < NHID; j += 64) s = fmaf(Qb[j], Kb[j], s);
#pragma unroll
      for (int o = 32; o > 0; o >>= 1) s += __shfl_down(s, o, 64);
      if (lane == 0) cbuf[0] = s;
      return;
    }
    float su = 0.f, sw = 0.f;
    for (int j = lane; j < NHID; j += 64) {
      su = fmaf(Qw[(size_t)k * NHID + j], Kb[j], su);
      sw = fmaf(Kw[(size_t)k * NHID + j], Qb[j], sw);
    }
#pragma unroll
    for (int o = 32; o > 0; o >>= 1) { su += __shfl_down(su, o, 64); sw += __shfl_down(sw, o, 64); }
    if (lane == 0) { u[k] = su; w[k] = sw; }
  } else {
    // bcat = [0 | Vb]; T = 0
    int i = (b - PB_MISC) * 256 + t;
    if (i < 1024) bcat[i] = (i < 512) ? 0.f : Vb[i - 512];
    else if (i < 1536) T[i - 1024] = 0.f;
  }
}

// ================= MFMA GEMM body =================
using frag_ab = __attribute__((ext_vector_type(8))) short;
using frag_cd = __attribute__((ext_vector_type(4))) float;

__device__ void mfma_gemm_body(int bx, int by, const ushort* __restrict__ A,
                               const ushort* __restrict__ Bt, const float* __restrict__ bias,
                               float* __restrict__ C, int ldc, float* __restrict__ Tsum,
                               ushort* Atile, ushort* Btile) {
  const int tid = threadIdx.x;
  const int w = tid >> 6, lane = tid & 63;
  const int m0 = by * 128, n0 = bx * 128;
  const int wm = (w >> 1) * 64, wn = (w & 1) * 64;
  const int q = lane >> 4, c16 = lane & 15;

  frag_cd acc[4][4];
#pragma unroll
  for (int i = 0; i < 4; ++i)
#pragma unroll
    for (int j = 0; j < 4; ++j) acc[i][j] = (frag_cd){0.f, 0.f, 0.f, 0.f};

  const int srow = (w << 3) + (lane >> 3);
  const int scolb = (lane & 7) << 4;
  const uint8_t* gA = (const uint8_t*)A + (size_t)(m0 + srow) * (KA_SPLIT * 2) + scolb;
  const uint8_t* gB = (const uint8_t*)Bt + (size_t)(n0 + srow) * (KB_SPLIT * 2) + scolb;

  for (int c = 0; c < 24; ++c) {
    const size_t kaB = (size_t)((c < 8 ? c : c - 8) * 128);
    const size_t kbB = (size_t)(c * 128);
#pragma unroll
    for (int r = 0; r < 4; ++r) {
      __builtin_amdgcn_global_load_lds(
          (const __attribute__((address_space(1))) uint32_t*)(gA + (size_t)(r * 32) * (KA_SPLIT * 2) + kaB),
          (__attribute__((address_space(3))) uint32_t*)((uint8_t*)Atile + r * 4096 + w * 1024), 16, 0, 0);
      __builtin_amdgcn_global_load_lds(
          (const __attribute__((address_space(1))) uint32_t*)(gB + (size_t)(r * 32) * (KB_SPLIT * 2) + kbB),
          (__attribute__((address_space(3))) uint32_t*)((uint8_t*)Btile + r * 4096 + w * 1024), 16, 0, 0);
    }
    __syncthreads();
#pragma unroll
    for (int kk = 0; kk < 2; ++kk) {
      frag_ab af[4], bf[4];
#pragma unroll
      for (int i = 0; i < 4; ++i) {
        af[i] = *(const frag_ab*)((const uint8_t*)Atile + (wm + i * 16 + c16) * 128 + kk * 64 + q * 16);
        bf[i] = *(const frag_ab*)((const uint8_t*)Btile + (wn + i * 16 + c16) * 128 + kk * 64 + q * 16);
      }
#pragma unroll
      for (int i = 0; i < 4; ++i)
#pragma unroll
        for (int j = 0; j < 4; ++j)
          acc[i][j] = __builtin_amdgcn_mfma_f32_16x16x32_bf16(af[i], bf[j], acc[i][j], 0, 0, 0);
    }
    __syncthreads();
  }
  // C/D layout: col = lane&15, row = (lane>>4)*4 + reg
#pragma unroll
  for (int j = 0; j < 4; ++j) {
    int col = n0 + wn + j * 16 + c16;
    float bv = bias ? bias[col] : 0.f;
    float csum = 0.f;
#pragma unroll
    for (int i = 0; i < 4; ++i) {
      int row = m0 + wm + i * 16 + q * 4;
#pragma unroll
      for (int r = 0; r < 4; ++r) {
        float v = acc[i][j][r] + bv;
        C[(size_t)(row + r) * ldc + col] = v;
        csum += v;
      }
    }
    if (Tsum && col >= 512) {  // fused T = colsum(Vh)
      csum += __shfl_xor(csum, 16, 64);
      csum += __shfl_xor(csum, 32, 64);
      if (q == 0) atomicAdd(&Tsum[col - 512], csum);
    }
  }
}

// ---------------- fp32 SGEMM body (small 512^3: M = Qw@Kw^T) ----------------
__device__ void sgemm_body(int bx, int by, const float* __restrict__ A, const float* __restrict__ B,
                           float* __restrict__ C, char* smem) {
  float(*As)[68] = (float(*)[68])smem;
  float(*Bs)[132] = (float(*)[132])(smem + 16 * 68 * 4);
  const int M = 512, Nn = 512, K = 512, ldc = 512;
  const int tid = threadIdx.x;
  const int bm = by * 64, bn = bx * 128;
  const int tx = tid & 15, ty = tid >> 4;
  const int arow = tid >> 2, acol = (tid & 3) << 2;
  const int brow = tid >> 4, bcol = (tid & 15) << 2;
  float acc[4][8];
#pragma unroll
  for (int i = 0; i < 4; ++i)
#pragma unroll
    for (int j = 0; j < 8; ++j) acc[i][j] = 0.f;
  const float* Ap = A + (size_t)(bm + arow) * K + acol;
  const float* Bp = B + (size_t)brow * Nn + bn + bcol;
  float4 av = *(const float4*)(Ap);
  float4 bv0 = *(const float4*)(Bp);
  float4 bv1 = *(const float4*)(Bp + 64);
  for (int k0 = 0; k0 < K; k0 += 16) {
    if (k0) __syncthreads();
    As[acol + 0][arow] = av.x;
    As[acol + 1][arow] = av.y;
    As[acol + 2][arow] = av.z;
    As[acol + 3][arow] = av.w;
    *(float4*)&Bs[brow][bcol] = bv0;
    *(float4*)&Bs[brow][bcol + 64] = bv1;
    __syncthreads();
    int kn = (k0 + 16 < K) ? k0 + 16 : 0;
    av = *(const float4*)(Ap + kn);
    bv0 = *(const float4*)(Bp + (size_t)kn * Nn);
    bv1 = *(const float4*)(Bp + (size_t)kn * Nn + 64);
#pragma unroll
    for (int kk = 0; kk < 16; ++kk) {
      float4 a = *(const float4*)&As[kk][ty << 2];
      float4 b0 = *(const float4*)&Bs[kk][tx << 2];
      float4 b1 = *(const float4*)&Bs[kk][(tx << 2) + 64];
      float ar[4] = {a.x, a.y, a.z, a.w};
      float br[8] = {b0.x, b0.y, b0.z, b0.w, b1.x, b1.y, b1.z, b1.w};
#pragma unroll
      for (int i = 0; i < 4; ++i)
#pragma unroll
        for (int j = 0; j < 8; ++j) acc[i][j] = fmaf(ar[i], br[j], acc[i][j]);
    }
  }
#pragma unroll
  for (int i = 0; i < 4; ++i) {
    int r = bm + (ty << 2) + i;
    *(float4*)(C + (size_t)r * ldc + bn + (tx << 2)) =
        make_float4(acc[i][0], acc[i][1], acc[i][2], acc[i][3]);
    *(float4*)(C + (size_t)r * ldc + bn + 64 + (tx << 2)) =
        make_float4(acc[i][4], acc[i][5], acc[i][6], acc[i][7]);
  }
  (void)M;
}

// ================= L2: gemm1 (xW = x@W1, 256 blocks) + sgemm (32 blocks) =================
__global__ __launch_bounds__(256) void gemm1_sgemm(
    const ushort* __restrict__ Xs, const ushort* __restrict__ W1ts, float* __restrict__ xW,
    const float* __restrict__ Qw, const float* __restrict__ KwT, float* __restrict__ Mmat) {
  __shared__ __align__(16) char smem[32768];
  int b = blockIdx.x;
  if (b < 256) {
    mfma_gemm_body(b & 3, b >> 2, Xs, W1ts, nullptr, xW, 512, nullptr,
                   (ushort*)smem, (ushort*)(smem + 16384));
  } else {
    sgemm_body((b - 256) & 3, (b - 256) >> 2, Qw, KwT, Mmat, smem);
  }
}

// ================= gemm2 standalone: [G|Vh] = h@[M|Vw] + bias, fused T =================
__global__ __launch_bounds__(256) void mfma_gemm2(const ushort* __restrict__ Hs,
                                                  const ushort* __restrict__ Bcts,
                                                  const float* __restrict__ bcat,
                                                  float* __restrict__ GVh, float* __restrict__ T) {
  __shared__ __align__(16) ushort Atile[128 * 64];
  __shared__ __align__(16) ushort Btile[128 * 64];
  mfma_gemm_body(blockIdx.x, blockIdx.y, Hs, Bcts, bcat, GVh, 1024, T, Atile, Btile);
}

// ================= L3: spmm (2048 blocks, first for co-residency) + split_mmat (768 blocks) =================
__global__ __launch_bounds__(256, 8) void spmm_split(
    const float* __restrict__ xW, const int* __restrict__ colidx, const int* __restrict__ deg,
    const float* __restrict__ b1, const float* __restrict__ u, const float* __restrict__ w,
    float* __restrict__ h, ushort* __restrict__ Hs,
    float* __restrict__ a_vec, float* __restrict__ b_vec,
    const float* __restrict__ Mm, ushort* __restrict__ Bt) {
  __shared__ int scols[SROWS][RCAP];
  __shared__ float4 part[128];
  __shared__ float ra[2], rb[2];
  int t = threadIdx.x;
  if (blockIdx.x >= N_NODES / SROWS) {
    // ---- split_mmat: Mmat columns -> Bcts rows [0,512) ----
    int idx = (blockIdx.x - N_NODES / SROWS) * 256 + t;
    int n = idx / 384, tc = idx % 384;
    const float* src = Mm + n;
    int sec = tc >> 7;
    int k0 = (tc & 127) << 2;
    ushort4 o;
    float f0 = src[(size_t)(k0 + 0) * 512];
    float f1 = src[(size_t)(k0 + 1) * 512];
    float f2 = src[(size_t)(k0 + 2) * 512];
    float f3 = src[(size_t)(k0 + 3) * 512];
    if (sec == 1) {
      o.x = f2bf(f0 - bf2f(f2bf(f0))); o.y = f2bf(f1 - bf2f(f2bf(f1)));
      o.z = f2bf(f2 - bf2f(f2bf(f2))); o.w = f2bf(f3 - bf2f(f2bf(f3)));
    } else {
      o.x = f2bf(f0); o.y = f2bf(f1); o.z = f2bf(f2); o.w = f2bf(f3);
    }
    ((ushort4*)(Bt + (size_t)n * KB_SPLIT))[tc] = o;
    return;
  }
  int half = t >> 7, tt = t & 127;
  int row0 = blockIdx.x * SROWS;
  int d[SROWS];
#pragma unroll
  for (int r = 0; r < SROWS; ++r) {
    d[r] = deg[row0 + r];
    for (int i = t; i < d[r]; i += 256) scols[r][i] = colidx[(size_t)(row0 + r) * RCAP + i];
  }
  __syncthreads();
#pragma unroll 1
  for (int r = 0; r < SROWS; ++r) {
    int row = row0 + r, dd = d[r];
    float4 acc = make_float4(0.f, 0.f, 0.f, 0.f);
    int e = half;  // this half takes edges of parity `half` (stride 2) -> same band phase
    for (; e + 14 < dd; e += 16) {
      float4 v0 = ((const float4*)(xW + (size_t)scols[r][e + 0] * NHID))[tt];
      float4 v1 = ((const float4*)(xW + (size_t)scols[r][e + 2] * NHID))[tt];
      float4 v2 = ((const float4*)(xW + (size_t)scols[r][e + 4] * NHID))[tt];
      float4 v3 = ((const float4*)(xW + (size_t)scols[r][e + 6] * NHID))[tt];
      float4 v4 = ((const float4*)(xW + (size_t)scols[r][e + 8] * NHID))[tt];
      float4 v5 = ((const float4*)(xW + (size_t)scols[r][e + 10] * NHID))[tt];
      float4 v6 = ((const float4*)(xW + (size_t)scols[r][e + 12] * NHID))[tt];
      float4 v7 = ((const float4*)(xW + (size_t)scols[r][e + 14] * NHID))[tt];
      acc.x += ((v0.x + v1.x) + (v2.x + v3.x)) + ((v4.x + v5.x) + (v6.x + v7.x));
      acc.y += ((v0.y + v1.y) + (v2.y + v3.y)) + ((v4.y + v5.y) + (v6.y + v7.y));
      acc.z += ((v0.z + v1.z) + (v2.z + v3.z)) + ((v4.z + v5.z) + (v6.z + v7.z));
      acc.w += ((v0.w + v1.w) + (v2.w + v3.w)) + ((v4.w + v5.w) + (v6.w + v7.w));
    }
    for (; e < dd; e += 2) {
      float4 v = ((const float4*)(xW + (size_t)scols[r][e] * NHID))[tt];
      acc.x += v.x; acc.y += v.y; acc.z += v.z; acc.w += v.w;
    }
    if (half == 1) part[tt] = acc;
    __syncthreads();
    if (half == 0) {
      float4 p = part[tt];
      acc.x += p.x; acc.y += p.y; acc.z += p.z; acc.w += p.w;
      float4 bv = ((const float4*)b1)[tt];
      float4 o = make_float4(fmaxf(acc.x + bv.x, 0.f), fmaxf(acc.y + bv.y, 0.f),
                             fmaxf(acc.z + bv.z, 0.f), fmaxf(acc.w + bv.w, 0.f));
      ((float4*)(h + (size_t)row * NHID))[tt] = o;
      ushort4 hi, lo;
      hi.x = f2bf(o.x); hi.y = f2bf(o.y); hi.z = f2bf(o.z); hi.w = f2bf(o.w);
      lo.x = f2bf(o.x - bf2f(hi.x)); lo.y = f2bf(o.y - bf2f(hi.y));
      lo.z = f2bf(o.z - bf2f(hi.z)); lo.w = f2bf(o.w - bf2f(hi.w));
      ushort* hr = Hs + (size_t)row * KA_SPLIT;
      ((ushort4*)hr)[tt] = hi;
      ((ushort4*)(hr + 512))[tt] = lo;
      float4 uv = ((const float4*)u)[tt], wv4 = ((const float4*)w)[tt];
      float sa = fmaf(o.x, uv.x, fmaf(o.y, uv.y, fmaf(o.z, uv.z, o.w * uv.w)));
      float sb = fmaf(o.x, wv4.x, fmaf(o.y, wv4.y, fmaf(o.z, wv4.z, o.w * wv4.w)));
      int wid = tt >> 6, lane = tt & 63;
#pragma unroll
      for (int off = 32; off > 0; off >>= 1) { sa += __shfl_down(sa, off, 64); sb += __shfl_down(sb, off, 64); }
      if (lane == 0) { ra[wid] = sa; rb[wid] = sb; }
    }
    __syncthreads();
    if (t == 0) { a_vec[row] = ra[0] + ra[1]; b_vec[row] = rb[0] + rb[1]; }
    __syncthreads();
  }
}

// ================= L5: score2 — 8-edge Phase A (8 gather chains in flight), no w2s LDS =================
// R8 measurement: 183us/rep, SQ_LDS_BANK_CONFLICT 1.57e8 (w2s epilogue: lane-stride 256B = same
// bank for all 64 lanes), Occupancy 22% (w2s = 16KB of 27KB LDS -> 5 blocks/CU), VALUBusy 15%
// (4 loads in flight). Fixes: W2 read from global (L2-resident, 16KB), Phase A step-8.
__global__ __launch_bounds__(256) void score2_agg_ln(
    const float* __restrict__ G, int ldg, const float* __restrict__ h,
    const ushort* __restrict__ Hs, const int* __restrict__ colidx, const int* __restrict__ deg,
    const float* __restrict__ a_vec, const float* __restrict__ b_vec,
    const float* __restrict__ cbuf, const float* __restrict__ Vh, int ldv,
    const float* __restrict__ T, const float* __restrict__ lng,
    const float* __restrict__ lnb, const float* __restrict__ W2, float* __restrict__ Y) {
  __shared__ int scols[4][RCAP];
  __shared__ float sbv[4][RCAP];
  __shared__ float sv[4][RCAP];
  __shared__ int cand[4][CANDCAP];
  __shared__ int ccnt[4];
  int t = threadIdx.x, wv = t >> 6, lane = t & 63;
  int row = blockIdx.x * 4 + wv;
  int d = deg[row];
  int q = lane >> 4, u = lane & 15;
  if (lane == 0) ccnt[wv] = 0;
  // exact fp32 G row -> quarter-wave-replicated registers.
  float4 ga4[4][2];
  const float4* Gr4 = (const float4*)(G + (size_t)row * ldg);
#pragma unroll
  for (int it2 = 0; it2 < 4; ++it2) {
    ga4[it2][0] = Gr4[it2 * 32 + 2 * u];
    ga4[it2][1] = Gr4[it2 * 32 + 2 * u + 1];
  }
  for (int i = lane; i < d; i += 64) {
    int c = colidx[(size_t)row * RCAP + i];
    scols[wv][i] = c;
    sbv[wv][i] = b_vec[c];
  }
  __syncthreads();
  // ---- Phase A: filter scores from bf16 h-hi, 8 edges per iteration (2 per 16-lane group) ----
  for (int e0 = 0; e0 < d; e0 += 8) {
    int eA = e0 + q, eB = e0 + 4 + q;
    bool actA = eA < d, actB = eB < d;
    int colA = scols[wv][actA ? eA : 0];
    int colB = scols[wv][actB ? eB : 0];
    const uint4* hrA = (const uint4*)(Hs + (size_t)colA * KA_SPLIT);  // hi = first 1 KB
    const uint4* hrB = (const uint4*)(Hs + (size_t)colB * KA_SPLIT);
    uint4 pA[4], pB[4];
#pragma unroll
    for (int it2 = 0; it2 < 4; ++it2) pA[it2] = hrA[it2 * 16 + u];
#pragma unroll
    for (int it2 = 0; it2 < 4; ++it2) pB[it2] = hrB[it2 * 16 + u];
    float sA_a = 0.f, sA_b = 0.f, sB_a = 0.f, sB_b = 0.f;
#pragma unroll
    for (int it2 = 0; it2 < 4; ++it2) {
      float4 g0 = ga4[it2][0], g1 = ga4[it2][1];
      uint4 p = pA[it2];
      sA_a = fmaf(__uint_as_float(p.x << 16), g0.x, sA_a);
      sA_a = fmaf(__uint_as_float(p.x & 0xffff0000u), g0.y, sA_a);
      sA_a = fmaf(__uint_as_float(p.y << 16), g0.z, sA_a);
      sA_a = fmaf(__uint_as_float(p.y & 0xffff0000u), g0.w, sA_a);
      sA_b = fmaf(__uint_as_float(p.z << 16), g1.x, sA_b);
      sA_b = fmaf(__uint_as_float(p.z & 0xffff0000u), g1.y, sA_b);
      sA_b = fmaf(__uint_as_float(p.w << 16), g1.z, sA_b);
      sA_b = fmaf(__uint_as_float(p.w & 0xffff0000u), g1.w, sA_b);
      uint4 r = pB[it2];
      sB_a = fmaf(__uint_as_float(r.x << 16), g0.x, sB_a);
      sB_a = fmaf(__uint_as_float(r.x & 0xffff0000u), g0.y, sB_a);
      sB_a = fmaf(__uint_as_float(r.y << 16), g0.z, sB_a);
      sB_a = fmaf(__uint_as_float(r.y & 0xffff0000u), g0.w, sB_a);
      sB_b = fmaf(__uint_as_float(r.z << 16), g1.x, sB_b);
      sB_b = fmaf(__uint_as_float(r.z & 0xffff0000u), g1.y, sB_b);
      sB_b = fmaf(__uint_as_float(r.w << 16), g1.z, sB_b);
      sB_b = fmaf(__uint_as_float(r.w & 0xffff0000u), g1.w, sB_b);
    }
    float sA = sA_a + sA_b;
    float sB = sB_a + sB_b;
    sA += __shfl_down(sA, 8, 16);
    sB += __shfl_down(sB, 8, 16);
    sA += __shfl_down(sA, 4, 16);
    sB += __shfl_down(sB, 4, 16);
    sA += __shfl_down(sA, 2, 16);
    sB += __shfl_down(sB, 2, 16);
    sA += __shfl_down(sA, 1, 16);
    sB += __shfl_down(sB, 1, 16);
    if (u == 0 && actA) sv[wv][eA] = sA + sbv[wv][eA];  // b_j affects ranking; a_i+c is row-const
    if (u == 0 && actB) sv[wv][eB] = sB + sbv[wv][eB];
  }
  __syncthreads();
  float fm = -1e30f;
  for (int i = lane; i < d; i += 64) fm = fmaxf(fm, sv[wv][i]);
#pragma unroll
  for (int o = 32; o > 0; o >>= 1) fm = fmaxf(fm, __shfl_xor(fm, o, 64));
  for (int i = lane; i < d; i += 64) {
    if (sv[wv][i] >= fm - FILTER_MARGIN) {
      int p = atomicAdd(&ccnt[wv], 1);
      if (p < CANDCAP) cand[wv][p] = i;
    }
  }
  __syncthreads();
  int nc = ccnt[wv];
  bool ovf = nc > CANDCAP;       // degenerate near-tie row: rescore ALL edges (rare, still exact)
  if (ovf) nc = d;
  float ai = a_vec[row] + cbuf[0];
  // ---- Phase B: exact fp32 rescore of candidates ----
  for (int c0 = 0; c0 < nc; c0 += 4) {
    int idx = c0 + q;
    bool act = idx < nc;
    int e = act ? (ovf ? idx : cand[wv][idx]) : 0;
    int col = scols[wv][e];
    const float4* hr = (const float4*)(h + (size_t)col * NHID);
    float s_a = 0.f, s_b = 0.f;
#pragma unroll
    for (int it2 = 0; it2 < 4; ++it2) {
      float4 h0 = hr[it2 * 32 + 2 * u], h1 = hr[it2 * 32 + 2 * u + 1];
      float4 g0 = ga4[it2][0], g1 = ga4[it2][1];
      s_a = fmaf(h0.x, g0.x, s_a); s_a = fmaf(h0.y, g0.y, s_a);
      s_a = fmaf(h0.z, g0.z, s_a); s_a = fmaf(h0.w, g0.w, s_a);
      s_b = fmaf(h1.x, g1.x, s_b); s_b = fmaf(h1.y, g1.y, s_b);
      s_b = fmaf(h1.z, g1.z, s_b); s_b = fmaf(h1.w, g1.w, s_b);
    }
    float s = s_a + s_b;
    s += __shfl_down(s, 8, 16);
    s += __shfl_down(s, 4, 16);
    s += __shfl_down(s, 2, 16);
    s += __shfl_down(s, 1, 16);
    if (u == 0 && act) sv[wv][e] = s + ai + sbv[wv][e];  // exact score
  }
  __syncthreads();
  // softmax over candidates + implicit background zeros (non-candidates contribute < e^-55)
  float m = 0.f;
  for (int i = lane; i < nc; i += 64) {
    int e = ovf ? i : cand[wv][i];
    m = fmaxf(m, sv[wv][e]);
  }
#pragma unroll
  for (int o = 32; o > 0; o >>= 1) m = fmaxf(m, __shfl_xor(m, o, 64));
  float ssum = 0.f;
  for (int i = lane; i < nc; i += 64) {
    int e = ovf ? i : cand[wv][i];
    float ex = expf(sv[wv][e] - m);
    sv[wv][e] = ex;
    ssum += ex;
  }
#pragma unroll
  for (int o = 32; o > 0; o >>= 1) ssum += __shfl_xor(ssum, o, 64);
  float em = expf(-m);
  float inv = 1.f / (ssum + (float)(N_NODES - d) * em);
  float ci = em * inv;
  __syncthreads();
  // aggregate candidate Vh rows (weight > 1e-12) + background*T, then LayerNorm
  float4 a0 = make_float4(0.f, 0.f, 0.f, 0.f), a1 = a0;
  for (int i = 0; i < nc; ++i) {
    int e = ovf ? i : cand[wv][i];
    float we = sv[wv][e] * inv;
    if (we > 1e-12f) {
      const float4* vr = (const float4*)(Vh + (size_t)scols[wv][e] * ldv);
      float4 v0 = vr[lane * 2], v1 = vr[lane * 2 + 1];
      a0.x = fmaf(we, v0.x, a0.x); a0.y = fmaf(we, v0.y, a0.y);
      a0.z = fmaf(we, v0.z, a0.z); a0.w = fmaf(we, v0.w, a0.w);
      a1.x = fmaf(we, v1.x, a1.x); a1.y = fmaf(we, v1.y, a1.y);
      a1.z = fmaf(we, v1.z, a1.z); a1.w = fmaf(we, v1.w, a1.w);
    }
  }
  float4 t0 = ((const float4*)T)[lane * 2], t1 = ((const float4*)T)[lane * 2 + 1];
  a0.x = fmaf(ci, t0.x, a0.x); a0.y = fmaf(ci, t0.y, a0.y);
  a0.z = fmaf(ci, t0.z, a0.z); a0.w = fmaf(ci, t0.w, a0.w);
  a1.x = fmaf(ci, t1.x, a1.x); a1.y = fmaf(ci, t1.y, a1.y);
  a1.z = fmaf(ci, t1.z, a1.z); a1.w = fmaf(ci, t1.w, a1.w);
  float s1 = ((a0.x + a0.y) + (a0.z + a0.w)) + ((a1.x + a1.y) + (a1.z + a1.w));
  float s2 = ((a0.x * a0.x + a0.y * a0.y) + (a0.z * a0.z + a0.w * a0.w)) +
             ((a1.x * a1.x + a1.y * a1.y) + (a1.z * a1.z + a1.w * a1.w));
#pragma unroll
  for (int o = 32; o > 0; o >>= 1) { s1 += __shfl_xor(s1, o, 64); s2 += __shfl_xor(s2, o, 64); }
  float mu = s1 * (1.f / NHID);
  float var = s2 * (1.f / NHID) - mu * mu;
  float rstd = rsqrtf(var + 1e-5f);
  float4 g0 = ((const float4*)lng)[lane * 2], g1 = ((const float4*)lng)[lane * 2 + 1];
  float4 b0 = ((const float4*)lnb)[lane * 2], b1v = ((const float4*)lnb)[lane * 2 + 1];
  float4 o0, o1;
  o0.x = (a0.x - mu) * rstd * g0.x + b0.x;
  o0.y = (a0.y - mu) * rstd * g0.y + b0.y;
  o0.z = (a0.z - mu) * rstd * g0.z + b0.z;
  o0.w = (a0.w - mu) * rstd * g0.w + b0.w;
  o1.x = (a1.x - mu) * rstd * g1.x + b1v.x;
  o1.y = (a1.y - mu) * rstd * g1.y + b1v.y;
  o1.z = (a1.z - mu) * rstd * g1.z + b1v.z;
  o1.w = (a1.w - mu) * rstd * g1.w + b1v.w;
  // fused Y = Xt @ W2 — W2 read straight from global (16KB, L2-resident; avoids the
  // w2s LDS bank-conflict storm: lane-stride 256B put all 64 lanes on one bank)
  float xv[8] = {o0.x, o0.y, o0.z, o0.w, o1.x, o1.y, o1.z, o1.w};
  const float4* W2v = (const float4*)W2;
  float4 acA = make_float4(0.f, 0.f, 0.f, 0.f), acB = acA;
#pragma unroll
  for (int kk = 0; kk < 8; ++kk) {
    int k = lane * 8 + kk;
    float4 wa = W2v[k * 2], wb = W2v[k * 2 + 1];
    acA.x = fmaf(xv[kk], wa.x, acA.x); acA.y = fmaf(xv[kk], wa.y, acA.y);
    acA.z = fmaf(xv[kk], wa.z, acA.z); acA.w = fmaf(xv[kk], wa.w, acA.w);
    acB.x = fmaf(xv[kk], wb.x, acB.x); acB.y = fmaf(xv[kk], wb.y, acB.y);
    acB.z = fmaf(xv[kk], wb.z, acB.z); acB.w = fmaf(xv[kk], wb.w, acB.w);
  }
  float accc[NCLASS] = {acA.x, acA.y, acA.z, acA.w, acB.x, acB.y, acB.z, acB.w};
#pragma unroll
  for (int c = 0; c < NCLASS; ++c)
#pragma unroll
    for (int o = 32; o > 0; o >>= 1) accc[c] += __shfl_down(accc[c], o, 64);
  if (lane == 0) {
    *(float4*)(Y + (size_t)row * NCLASS) = make_float4(accc[0], accc[1], accc[2], accc[3]);
    *(float4*)(Y + (size_t)row * NCLASS + 4) = make_float4(accc[4], accc[5], accc[6], accc[7]);
  }
}

// ================= L6: z = adj @ Y + b2, softmax over 8 classes =================
__global__ __launch_bounds__(256) void final_spmm_softmax(const float* __restrict__ Y,
                                                          const int* __restrict__ colidx,
                                                          const int* __restrict__ deg,
                                                          const float* __restrict__ b2,
                                                          float* __restrict__ out) {
  int t = threadIdx.x;
  int wv = t >> 6, lane = t & 63;
  int row = blockIdx.x * 4 + wv;
  int d = deg[row];
  const int* cols = colidx + (size_t)row * RCAP;
  float acc[8];
#pragma unroll
  for (int c = 0; c < 8; ++c) acc[c] = 0.f;
  for (int e = lane; e < d; e += 64) {
    int col = cols[e];
    const float4* yr = (const float4*)(Y + (size_t)col * 8);
    float4 y0 = yr[0], y1 = yr[1];
    acc[0] += y0.x; acc[1] += y0.y; acc[2] += y0.z; acc[3] += y0.w;
    acc[4] += y1.x; acc[5] += y1.y; acc[6] += y1.z; acc[7] += y1.w;
  }
#pragma unroll
  for (int c = 0; c < 8; ++c)
#pragma unroll
    for (int o = 32; o > 0; o >>= 1) acc[c] += __shfl_down(acc[c], o, 64);
  if (lane == 0) {
    float z[8];
    float m = -1e30f;
#pragma unroll
    for (int c = 0; c < 8; ++c) { z[c] = acc[c] + b2[c]; m = fmaxf(m, z[c]); }
    float s = 0.f;
#pragma unroll
    for (int c = 0; c < 8; ++c) { z[c] = expf(z[c] - m); s += z[c]; }
    float inv = 1.f / s;
    *(float4*)(out + (size_t)row * 8) = make_float4(z[0] * inv, z[1] * inv, z[2] * inv, z[3] * inv);
    *(float4*)(out + (size_t)row * 8 + 4) = make_float4(z[4] * inv, z[5] * inv, z[6] * inv, z[7] * inv);
  }
}

extern "C" void kernel_launch(void* const* d_in, const int* in_sizes, int n_in,
                              void* d_out, int out_size, void* d_ws, size_t ws_size,
                              hipStream_t stream) {
  const float* adj = (const float*)d_in[0];
  const float* x = (const float*)d_in[1];
  const float* W1 = (const float*)d_in[2];
  const float* b1 = (const float*)d_in[3];
  const float* Qw = (const float*)d_in[4];
  const float* Qb = (const float*)d_in[5];
  const float* Kw = (const float*)d_in[6];
  const float* Kb = (const float*)d_in[7];
  const float* Vw = (const float*)d_in[8];
  const float* Vb = (const float*)d_in[9];
  const float* ln_g = (const float*)d_in[10];
  const float* ln_b = (const float*)d_in[11];
  const float* W2 = (const float*)d_in[12];
  const float* b2 = (const float*)d_in[13];
  float* out = (float*)d_out;

  char* ws = (char*)d_ws;
  size_t off = 0;
  auto alloc = [&](size_t bytes) -> void* {
    void* p = ws + off;
    off = (off + bytes + 255) & ~(size_t)255;
    return p;
  };
  int* colidx = (int*)alloc((size_t)N_NODES * RCAP * 4);
  int* deg = (int*)alloc((size_t)N_NODES * 4);
  float* bufA = (float*)alloc((size_t)N_NODES * NHID * 4);     // xW
  float* bufB = (float*)alloc((size_t)N_NODES * NHID * 4);     // h
  float* GVh = (float*)alloc((size_t)N_NODES * 1024 * 4);      // [G | Vh], stride 1024
  ushort* Xs = (ushort*)alloc((size_t)N_NODES * KA_SPLIT * 2); // split x [hi|lo]
  ushort* Hs = (ushort*)alloc((size_t)N_NODES * KA_SPLIT * 2); // split h [hi|lo]
  ushort* W1ts = (ushort*)alloc((size_t)512 * KB_SPLIT * 2);   // split W1^T [hi|lo|hi]
  ushort* Bcts = (ushort*)alloc((size_t)1024 * KB_SPLIT * 2);  // split [M|Vw]^T
  float* KwT = (float*)alloc((size_t)512 * 512 * 4);
  float* Mmat = (float*)alloc((size_t)512 * 512 * 4);
  float* bcat = (float*)alloc((size_t)1024 * 4);
  float* a_vec = (float*)alloc((size_t)N_NODES * 4);
  float* b_vec = (float*)alloc((size_t)N_NODES * 4);
  float* u_vec = (float*)alloc((size_t)NHID * 4);
  float* w_vec = (float*)alloc((size_t)NHID * 4);
  float* cbuf = (float*)alloc(256);
  float* T = (float*)alloc((size_t)NHID * 4);
  float* Y = (float*)alloc((size_t)N_NODES * NCLASS * 4);
  (void)in_sizes; (void)n_in; (void)out_size; (void)ws_size;

  // L1) build_ell + all input prep (independent work, one launch)
  build_prep<<<N_NODES + PB_TOTAL, 256, 0, stream>>>(
      adj, colidx, deg, Kw, KwT, x, Xs, W1, W1ts, Vw, Bcts,
      Qw, Qb, Kb, u_vec, w_vec, cbuf, Vb, bcat, T);
  // L2) xW = x@W1 (MFMA) + M = Qw@Kw^T (fp32) — both depend only on L1
  gemm1_sgemm<<<256 + 32, 256, 0, stream>>>(Xs, W1ts, bufA, Qw, KwT, Mmat);
  // L3) h = relu(adj@xW + b1) (band-swept co-resident SpMM) + Mmat->Bcts split
  spmm_split<<<N_NODES / SROWS + 768, 256, 0, stream>>>(
      bufA, colidx, deg, b1, u_vec, w_vec, bufB, Hs, a_vec, b_vec, Mmat, Bcts);
  // L4) [G | Vh] = h @ [M | Vw] (+[0|Vb]) via MFMA, fused T = colsum(Vh)
  mfma_gemm2<<<dim3(8, 64), 256, 0, stream>>>(Hs, Bcts, bcat, GVh, T);
  // L5) two-level scores + softmax + aggregate + LN + fused W2 -> Y
  score2_agg_ln<<<N_NODES / 4, 256, 0, stream>>>(GVh, 1024, bufB, Hs, colidx, deg, a_vec, b_vec,
                                                 cbuf, GVh + 512, 1024, T, ln_g, ln_b, W2, Y);
  // L6) z = adj @ Y + b2 ; softmax
  final_spmm_softmax<<<N_NODES / 4, 256, 0, stream>>>(Y, colidx, deg, b2, out);
}